// Round 1
// 700.743 us; speedup vs baseline: 1.0089x; 1.0089x over previous
//
#include <hip/hip_runtime.h>
#include <math.h>

// GraphTransformer fused: RMSNorm(q,k) + edge attention + segment softmax.
// q,k,v:[N,H,C] f32; e:[E,H,C] f32; w_*:[C]; edge_src random; edge_dst SORTED.
// H=8, C=32.
//
// 2 kernels on one stream:
//  1) build_pre: blocks [0,KB) compute kscale[n,h]=rsqrt(mean(k[n,h,:]^2)+eps);
//                blocks [KB,..) compute offs[d]=lower_bound(edge_dst,d) (CSR).
//     Fused so the binary-search latency hides under the k-row streaming.
//  2) gt_attn_main: 1 wave per dst; lane = head(tid>>3) x chanquad(tid&7);
//     4-edge-unrolled online softmax (12 KB gather bytes in flight per wave);
//     e streamed nontemporally and issued before the esrc-dependent gathers.

#define Hh 8
#define Cc 32
#define HC 256
#define EPSf 1e-6f

typedef float v4f __attribute__((ext_vector_type(4)));

__global__ __launch_bounds__(256) void build_pre(
    const float* __restrict__ k, const int* __restrict__ edst,
    int* __restrict__ offs, float* __restrict__ kscale,
    int N, int E, int KB)
{
    const int b = blockIdx.x;
    if (b < KB) {
        const int wave = threadIdx.x >> 6, lane = threadIdx.x & 63;
        const int n = b * 4 + wave;
        if (n >= N) return;
        const v4f k4 = *(const v4f*)(k + (size_t)n * HC + lane * 4);
        float ss = k4.x*k4.x + k4.y*k4.y + k4.z*k4.z + k4.w*k4.w;
        ss += __shfl_xor(ss, 1); ss += __shfl_xor(ss, 2); ss += __shfl_xor(ss, 4);
        if ((lane & 7) == 0)
            kscale[n * Hh + (lane >> 3)] = rsqrtf(ss * (1.0f / Cc) + EPSf);
    } else {
        const int d = (b - KB) * 256 + threadIdx.x;
        if (d > N) return;
        int lo = 0, r = E;
        while (lo < r) { int mid = (lo + r) >> 1; if (edst[mid] < d) lo = mid + 1; else r = mid; }
        offs[d] = lo;
    }
}

__global__ __launch_bounds__(256, 4) void gt_attn_main(
    const float* __restrict__ q,
    const float* __restrict__ k,
    const float* __restrict__ v,
    const float* __restrict__ e,
    const float* __restrict__ wq,
    const float* __restrict__ wk,
    const int*   __restrict__ esrc,
    const int*   __restrict__ offs,
    const float* __restrict__ kscale,
    float*       __restrict__ out,
    int N)
{
    const int wave = threadIdx.x >> 6, lane = threadIdx.x & 63;
    const int d = blockIdx.x * 4 + wave;
    if (d >= N) return;
    const int h  = lane >> 3;
    const int cq = (lane & 7) * 4;

    const int lo = offs[d], hi = offs[d + 1];

    const v4f wq4 = *(const v4f*)(wq + cq);
    const v4f wk4 = *(const v4f*)(wk + cq);

    // qn = RMSNorm(q[d]) * wq
    const v4f q4 = *(const v4f*)(q + (size_t)d * HC + lane * 4);
    float ss = q4.x*q4.x + q4.y*q4.y + q4.z*q4.z + q4.w*q4.w;
    ss += __shfl_xor(ss, 1); ss += __shfl_xor(ss, 2); ss += __shfl_xor(ss, 4);
    const v4f qn = q4 * (rsqrtf(ss * (1.0f / Cc) + EPSf)) * wq4;

    const float qk_scale = rsqrtf((float)Cc);

    float m = -INFINITY, l = 0.0f;
    v4f acc = {0.f, 0.f, 0.f, 0.f};

    int ei = lo;

    // ---- 4-edge unrolled main loop: 12 dwordx4 gathers in flight per wave ----
    for (; ei + 3 < hi; ei += 4) {
        // e loads are independent of esrc -> issue first
        const v4f e0 = __builtin_nontemporal_load((const v4f*)(e + (size_t)(ei + 0) * HC + lane * 4));
        const v4f e1 = __builtin_nontemporal_load((const v4f*)(e + (size_t)(ei + 1) * HC + lane * 4));
        const v4f e2 = __builtin_nontemporal_load((const v4f*)(e + (size_t)(ei + 2) * HC + lane * 4));
        const v4f e3 = __builtin_nontemporal_load((const v4f*)(e + (size_t)(ei + 3) * HC + lane * 4));

        const int s0 = esrc[ei], s1 = esrc[ei + 1], s2 = esrc[ei + 2], s3 = esrc[ei + 3];

        const v4f k0 = *(const v4f*)(k + (size_t)s0 * HC + lane * 4);
        const v4f k1 = *(const v4f*)(k + (size_t)s1 * HC + lane * 4);
        const v4f k2 = *(const v4f*)(k + (size_t)s2 * HC + lane * 4);
        const v4f k3 = *(const v4f*)(k + (size_t)s3 * HC + lane * 4);
        const v4f v0 = *(const v4f*)(v + (size_t)s0 * HC + lane * 4);
        const v4f v1 = *(const v4f*)(v + (size_t)s1 * HC + lane * 4);
        const v4f v2 = *(const v4f*)(v + (size_t)s2 * HC + lane * 4);
        const v4f v3 = *(const v4f*)(v + (size_t)s3 * HC + lane * 4);
        const float r0 = kscale[s0 * Hh + h];
        const float r1 = kscale[s1 * Hh + h];
        const float r2 = kscale[s2 * Hh + h];
        const float r3 = kscale[s3 * Hh + h];

        const v4f ke0 = k0 * r0 * wk4 + e0;
        const v4f ke1 = k1 * r1 * wk4 + e1;
        const v4f ke2 = k2 * r2 * wk4 + e2;
        const v4f ke3 = k3 * r3 * wk4 + e3;
        const v4f ve0 = v0 + e0;
        const v4f ve1 = v1 + e1;
        const v4f ve2 = v2 + e2;
        const v4f ve3 = v3 + e3;

        float t0 = qn.x*ke0.x + qn.y*ke0.y + qn.z*ke0.z + qn.w*ke0.w;
        float t1 = qn.x*ke1.x + qn.y*ke1.y + qn.z*ke1.z + qn.w*ke1.w;
        float t2 = qn.x*ke2.x + qn.y*ke2.y + qn.z*ke2.z + qn.w*ke2.w;
        float t3 = qn.x*ke3.x + qn.y*ke3.y + qn.z*ke3.z + qn.w*ke3.w;

        // 4 interleaved shuffle-reduce chains (C=32 -> 8-lane group, 3 rounds)
        t0 += __shfl_xor(t0, 1); t1 += __shfl_xor(t1, 1); t2 += __shfl_xor(t2, 1); t3 += __shfl_xor(t3, 1);
        t0 += __shfl_xor(t0, 2); t1 += __shfl_xor(t1, 2); t2 += __shfl_xor(t2, 2); t3 += __shfl_xor(t3, 2);
        t0 += __shfl_xor(t0, 4); t1 += __shfl_xor(t1, 4); t2 += __shfl_xor(t2, 4); t3 += __shfl_xor(t3, 4);
        t0 *= qk_scale; t1 *= qk_scale; t2 *= qk_scale; t3 *= qk_scale;

        const float mx = fmaxf(fmaxf(t0, t1), fmaxf(t2, t3));
        const float mn = fmaxf(m, mx);
        const float al = __expf(m - mn);            // exp(-inf)=0 on first group
        const float p0 = __expf(t0 - mn);
        const float p1 = __expf(t1 - mn);
        const float p2 = __expf(t2 - mn);
        const float p3 = __expf(t3 - mn);
        l = l * al + ((p0 + p1) + (p2 + p3));
        acc = acc * al + ((p0 * ve0 + p1 * ve1) + (p2 * ve2 + p3 * ve3));
        m = mn;
    }

    // ---- 2-edge tail ----
    for (; ei + 1 < hi; ei += 2) {
        const v4f ea = __builtin_nontemporal_load((const v4f*)(e + (size_t)ei * HC + lane * 4));
        const v4f eb = __builtin_nontemporal_load((const v4f*)(e + (size_t)(ei + 1) * HC + lane * 4));
        const int s0 = esrc[ei], s1 = esrc[ei + 1];
        const v4f ka = *(const v4f*)(k + (size_t)s0 * HC + lane * 4);
        const v4f kb = *(const v4f*)(k + (size_t)s1 * HC + lane * 4);
        const v4f va = *(const v4f*)(v + (size_t)s0 * HC + lane * 4);
        const v4f vb = *(const v4f*)(v + (size_t)s1 * HC + lane * 4);
        const float krsa = kscale[s0 * Hh + h];
        const float krsb = kscale[s1 * Hh + h];

        const v4f kea = ka * krsa * wk4 + ea;
        const v4f keb = kb * krsb * wk4 + eb;

        float sa = qn.x*kea.x + qn.y*kea.y + qn.z*kea.z + qn.w*kea.w;
        float sb = qn.x*keb.x + qn.y*keb.y + qn.z*keb.z + qn.w*keb.w;
        sa += __shfl_xor(sa, 1); sb += __shfl_xor(sb, 1);
        sa += __shfl_xor(sa, 2); sb += __shfl_xor(sb, 2);
        sa += __shfl_xor(sa, 4); sb += __shfl_xor(sb, 4);
        sa *= qk_scale; sb *= qk_scale;

        const float mn = fmaxf(m, fmaxf(sa, sb));
        const float al = __expf(m - mn);
        const float pa = __expf(sa - mn);
        const float pb = __expf(sb - mn);
        l = l * al + pa + pb;
        acc = acc * al + pa * (va + ea) + pb * (vb + eb);
        m = mn;
    }

    // ---- 1-edge tail ----
    if (ei < hi) {
        const int s0 = esrc[ei];
        const v4f ka = *(const v4f*)(k + (size_t)s0 * HC + lane * 4);
        const v4f ea = __builtin_nontemporal_load((const v4f*)(e + (size_t)ei * HC + lane * 4));
        const v4f va = *(const v4f*)(v + (size_t)s0 * HC + lane * 4);
        const float krsa = kscale[s0 * Hh + h];
        const v4f kea = ka * krsa * wk4 + ea;
        float sa = qn.x*kea.x + qn.y*kea.y + qn.z*kea.z + qn.w*kea.w;
        sa += __shfl_xor(sa, 1); sa += __shfl_xor(sa, 2); sa += __shfl_xor(sa, 4);
        sa *= qk_scale;
        const float mn = fmaxf(m, sa);
        const float al = __expf(m - mn);
        const float pa = __expf(sa - mn);
        l = l * al + pa;
        acc = acc * al + pa * (va + ea);
        m = mn;
    }

    v4f o = {0.f, 0.f, 0.f, 0.f};
    if (l > 0.0f) o = acc * (1.0f / l);
    __builtin_nontemporal_store(o, (v4f*)(out + (size_t)d * HC + lane * 4));
}

extern "C" void kernel_launch(void* const* d_in, const int* in_sizes, int n_in,
                              void* d_out, int out_size, void* d_ws, size_t ws_size,
                              hipStream_t stream) {
    const float* q   = (const float*)d_in[0];
    const float* k   = (const float*)d_in[1];
    const float* v   = (const float*)d_in[2];
    const float* e   = (const float*)d_in[3];
    const float* wq  = (const float*)d_in[4];
    const float* wk  = (const float*)d_in[5];
    const int* esrc  = (const int*)d_in[6];
    const int* edst  = (const int*)d_in[7];
    float* out       = (float*)d_out;

    const int E  = in_sizes[6];
    const int hc = in_sizes[3] / E;     // H*C (expect 256)
    const int N  = in_sizes[0] / hc;

    // workspace layout: offs[N+1] ints, then kscale[N*H] floats
    int*   offs   = (int*)d_ws;
    float* kscale = (float*)((char*)d_ws + ((size_t)(N + 1) * sizeof(int) + 255 & ~(size_t)255));

    const int KB = (N + 3) / 4;               // kscale blocks (4 rows each)
    const int OB = (N + 1 + 255) / 256;       // offs blocks

    build_pre   <<<dim3(KB + OB), dim3(256), 0, stream>>>(k, edst, offs, kscale, N, E, KB);
    gt_attn_main<<<dim3((N + 3) / 4), dim3(256), 0, stream>>>(
        q, k, v, e, wq, wk, esrc, offs, kscale, out, N);
}